// Round 1
// baseline (477.067 us; speedup 1.0000x reference)
//
#include <hip/hip_runtime.h>

// patient_GCN: 2x GCNConv(128->128) + mean-pool + head, fp32.
// Strategy: build CSR (by dst) once per launch, reuse for both conv layers.
//   deg -> dinv ; h = x@W (tiled fp32 GEMM) ; agg = pull-gather over CSR
//   + analytic self-loop ; pool via sorted batch ; small fused head.

#define NFEAT 128

// ---------------- CSR build ----------------
__global__ void k_deg(const int* __restrict__ dst, int* __restrict__ cnt, int E) {
  int e = blockIdx.x * 256 + threadIdx.x;
  if (e < E) atomicAdd(&cnt[dst[e]], 1);
}

__global__ void k_part(const int* __restrict__ cnt, int* __restrict__ part, int n) {
  __shared__ int s[256];
  int t = threadIdx.x;
  int idx = blockIdx.x * 256 + t;
  s[t] = (idx < n) ? cnt[idx] : 0;
  __syncthreads();
  for (int o = 128; o > 0; o >>= 1) {
    if (t < o) s[t] += s[t + o];
    __syncthreads();
  }
  if (t == 0) part[blockIdx.x] = s[0];
}

// single block: exclusive scan of NB (<=256) partials; also writes offs[n]=total
__global__ void k_scan1(const int* __restrict__ part, int* __restrict__ ppre,
                        int NB, int* __restrict__ offs, int n) {
  __shared__ int s[256];
  int t = threadIdx.x;
  int v = (t < NB) ? part[t] : 0;
  s[t] = v;
  __syncthreads();
  for (int o = 1; o < 256; o <<= 1) {
    int tmp = (t >= o) ? s[t - o] : 0;
    __syncthreads();
    s[t] += tmp;
    __syncthreads();
  }
  if (t < NB) ppre[t] = s[t] - v;
  if (t == NB - 1) offs[n] = s[t];
}

__global__ void k_offsets(const int* __restrict__ cnt, const int* __restrict__ ppre,
                          int* __restrict__ offs, int* __restrict__ cursor, int n) {
  __shared__ int s[256];
  int t = threadIdx.x;
  int idx = blockIdx.x * 256 + t;
  int v = (idx < n) ? cnt[idx] : 0;
  s[t] = v;
  __syncthreads();
  for (int o = 1; o < 256; o <<= 1) {
    int tmp = (t >= o) ? s[t - o] : 0;
    __syncthreads();
    s[t] += tmp;
    __syncthreads();
  }
  if (idx < n) {
    int off = ppre[blockIdx.x] + s[t] - v;
    offs[idx] = off;
    cursor[idx] = off;
  }
}

__global__ void k_fill(const int* __restrict__ src, const int* __restrict__ dst,
                       int* __restrict__ cursor, int* __restrict__ csr, int E) {
  int e = blockIdx.x * 256 + threadIdx.x;
  if (e < E) {
    int p = atomicAdd(&cursor[dst[e]], 1);
    csr[p] = src[e];
  }
}

__global__ void k_dinv(const int* __restrict__ cnt, float* __restrict__ dinv, int n) {
  int i = blockIdx.x * 256 + threadIdx.x;
  if (i < n) dinv[i] = rsqrtf((float)(cnt[i] + 1));  // +1 self-loop, deg>=1
}

// ---------------- GEMM: H[M,128] = X[M,128] @ W[128,128] ----------------
// BM=64, full N=128, K chunked by 64. LDS: W-chunk 32KB + X-tile 16KB = 48KB.
// 256 thr: tx=col/4 (0..31), ty=row-group (0..7), 8 rows x 4 cols per thread.
__global__ __launch_bounds__(256) void k_gemm128(const float* __restrict__ X,
                                                 const float* __restrict__ W,
                                                 float* __restrict__ H, int M) {
  __shared__ float sW[64 * 128];
  __shared__ float sX[64 * 64];
  int tid = threadIdx.x;
  int tx = tid & 31, ty = tid >> 5;
  int m0 = blockIdx.x * 64;
  float4 acc[8];
#pragma unroll
  for (int r = 0; r < 8; r++) acc[r] = make_float4(0.f, 0.f, 0.f, 0.f);
  const float4* W4 = (const float4*)W;
  float4* sW4 = (float4*)sW;

  for (int ko = 0; ko < 128; ko += 64) {
    // stage W rows [ko, ko+64): 2048 float4
#pragma unroll
    for (int i = tid; i < 2048; i += 256) sW4[i] = W4[ko * 32 + i];
    // stage X tile [m0,m0+64) x [ko,ko+64): 1024 float4
#pragma unroll
    for (int i = tid; i < 1024; i += 256) {
      int r = i >> 4, c = i & 15;
      int rowg = m0 + r;
      float4 v = make_float4(0.f, 0.f, 0.f, 0.f);
      if (rowg < M) v = *(const float4*)(X + (size_t)rowg * 128 + ko + c * 4);
      *(float4*)&sX[r * 64 + c * 4] = v;
    }
    __syncthreads();
#pragma unroll
    for (int kk = 0; kk < 64; kk += 4) {
      float4 w0 = sW4[(kk + 0) * 32 + tx];
      float4 w1 = sW4[(kk + 1) * 32 + tx];
      float4 w2 = sW4[(kk + 2) * 32 + tx];
      float4 w3 = sW4[(kk + 3) * 32 + tx];
#pragma unroll
      for (int r = 0; r < 8; r++) {
        float4 xv = *(const float4*)&sX[(ty * 8 + r) * 64 + kk];
        acc[r].x += xv.x * w0.x + xv.y * w1.x + xv.z * w2.x + xv.w * w3.x;
        acc[r].y += xv.x * w0.y + xv.y * w1.y + xv.z * w2.y + xv.w * w3.y;
        acc[r].z += xv.x * w0.z + xv.y * w1.z + xv.z * w2.z + xv.w * w3.z;
        acc[r].w += xv.x * w0.w + xv.y * w1.w + xv.z * w2.w + xv.w * w3.w;
      }
    }
    __syncthreads();
  }
#pragma unroll
  for (int r = 0; r < 8; r++) {
    int rowg = m0 + ty * 8 + r;
    if (rowg < M) *(float4*)(H + (size_t)rowg * 128 + tx * 4) = acc[r];
  }
}

// ---------------- Aggregation: one wave per node, lane = float2 ----------------
// out[i] = relu(b + dinv[i]*sum_{e in(i)} dinv[src]*h[src] + dinv[i]^2*h[i])
__global__ __launch_bounds__(256) void k_agg(const float* __restrict__ H,
                                             const int* __restrict__ csr,
                                             const int* __restrict__ offs,
                                             const float* __restrict__ dinv,
                                             const float* __restrict__ bias,
                                             float* __restrict__ Ho, int n) {
  int lane = threadIdx.x & 63;
  int i = blockIdx.x * 4 + (threadIdx.x >> 6);
  if (i >= n) return;
  const float2* H2 = (const float2*)H;
  float di = dinv[i];
  float2 self = H2[(size_t)i * 64 + lane];
  int e0 = offs[i], e1 = offs[i + 1];
  float ax = 0.f, ay = 0.f;
  int e = e0;
  // two independent gathers in flight
  for (; e + 1 < e1; e += 2) {
    int s0 = csr[e], s1 = csr[e + 1];
    float d0 = dinv[s0], d1 = dinv[s1];
    float2 h0 = H2[(size_t)s0 * 64 + lane];
    float2 h1 = H2[(size_t)s1 * 64 + lane];
    ax += d0 * h0.x + d1 * h1.x;
    ay += d0 * h0.y + d1 * h1.y;
  }
  if (e < e1) {
    int s0 = csr[e];
    float d0 = dinv[s0];
    float2 h0 = H2[(size_t)s0 * 64 + lane];
    ax += d0 * h0.x;
    ay += d0 * h0.y;
  }
  const float2* B2 = (const float2*)bias;
  float2 b = B2[lane];
  float ox = b.x + di * ax + di * di * self.x;
  float oy = b.y + di * ay + di * di * self.y;
  float2 o;
  o.x = ox > 0.f ? ox : 0.f;
  o.y = oy > 0.f ? oy : 0.f;
  ((float2*)Ho)[(size_t)i * 64 + lane] = o;
}

// ---------------- Mean pool over sorted batch ----------------
__global__ void k_pool(const float* __restrict__ H, const int* __restrict__ batch,
                       float* __restrict__ pooled, int n, int G) {
  int g = blockIdx.x, t = threadIdx.x;  // 128 threads
  __shared__ int sb[2];
  if (t < 2) {
    int target = g + t;
    int lo = 0, hi = n;
    while (lo < hi) {
      int mid = (lo + hi) >> 1;
      if (batch[mid] < target) lo = mid + 1; else hi = mid;
    }
    sb[t] = lo;
  }
  __syncthreads();
  int s = sb[0], epos = sb[1];
  float sum = 0.f;
  for (int r = s; r < epos; r++) sum += H[(size_t)r * 128 + t];
  int c = epos - s;
  if (c < 1) c = 1;
  pooled[g * 128 + t] = sum / (float)c;
}

// ---------------- Head: g=pooled@l1W+l1b, a=ax@axW+axb, out=[g|a]@l2W+l2b ----------------
__global__ void k_head(const float* __restrict__ pooled, const float* __restrict__ axd,
                       const float* __restrict__ l1W, const float* __restrict__ l1b,
                       const float* __restrict__ axW, const float* __restrict__ axb,
                       const float* __restrict__ l2W, const float* __restrict__ l2b,
                       float* __restrict__ out, int G) {
  int g = blockIdx.x, t = threadIdx.x;  // 128 threads
  __shared__ float z[192];
  __shared__ float p[128];
  __shared__ float a[64];
  p[t] = pooled[g * 128 + t];
  if (t < 64) a[t] = axd[g * 64 + t];
  __syncthreads();
  float accg = l1b[t];
  for (int k = 0; k < 128; k++) accg += p[k] * l1W[k * 128 + t];
  z[t] = accg;
  if (t < 64) {
    float acca = axb[t];
    for (int k = 0; k < 64; k++) acca += a[k] * axW[k * 64 + t];
    z[128 + t] = acca;
  }
  __syncthreads();
  if (t < 8) {
    float acc = l2b[t];
    for (int k = 0; k < 192; k++) acc += z[k] * l2W[k * 8 + t];
    out[g * 8 + t] = acc;
  }
}

extern "C" void kernel_launch(void* const* d_in, const int* in_sizes, int n_in,
                              void* d_out, int out_size, void* d_ws, size_t ws_size,
                              hipStream_t stream) {
  const float* x   = (const float*)d_in[0];
  const int*   ei  = (const int*)d_in[1];
  const int*   bat = (const int*)d_in[2];
  const float* axd = (const float*)d_in[3];
  const float* W1  = (const float*)d_in[4];
  const float* b1  = (const float*)d_in[5];
  const float* W2  = (const float*)d_in[6];
  const float* b2  = (const float*)d_in[7];
  const float* l1W = (const float*)d_in[8];
  const float* l1b = (const float*)d_in[9];
  const float* axW = (const float*)d_in[10];
  const float* axb = (const float*)d_in[11];
  const float* l2W = (const float*)d_in[12];
  const float* l2b = (const float*)d_in[13];
  float* out = (float*)d_out;

  int n = in_sizes[0] / NFEAT;   // 50000
  int E = in_sizes[1] / 2;       // 640000
  int G = in_sizes[3] / 64;      // 512

  // workspace layout (fp32/int32, 16B-aligned chunks)
  float* hbuf   = (float*)d_ws;                       // n*128
  float* habuf  = hbuf + (size_t)n * NFEAT;           // n*128
  int*   csr    = (int*)(habuf + (size_t)n * NFEAT);  // E
  int*   offs   = csr + E;                            // n+1
  int*   cursor = offs + (n + 1);                     // n
  int*   cnt    = cursor + n;                         // n
  float* dinv   = (float*)(cnt + n);                  // n
  int*   part   = (int*)(dinv + n);                   // 256
  int*   ppre   = part + 256;                         // 256
  float* pooled = (float*)(ppre + 256);               // G*128

  const int* srcv = ei;
  const int* dstv = ei + E;
  int NB = (n + 255) / 256;  // 196 <= 256

  hipMemsetAsync(cnt, 0, (size_t)n * sizeof(int), stream);
  k_deg<<<(E + 255) / 256, 256, 0, stream>>>(dstv, cnt, E);
  k_part<<<NB, 256, 0, stream>>>(cnt, part, n);
  k_scan1<<<1, 256, 0, stream>>>(part, ppre, NB, offs, n);
  k_offsets<<<NB, 256, 0, stream>>>(cnt, ppre, offs, cursor, n);
  k_fill<<<(E + 255) / 256, 256, 0, stream>>>(srcv, dstv, cursor, csr, E);
  k_dinv<<<(n + 255) / 256, 256, 0, stream>>>(cnt, dinv, n);

  k_gemm128<<<(n + 63) / 64, 256, 0, stream>>>(x, W1, hbuf, n);
  k_agg<<<(n + 3) / 4, 256, 0, stream>>>(hbuf, csr, offs, dinv, b1, habuf, n);
  k_gemm128<<<(n + 63) / 64, 256, 0, stream>>>(habuf, W2, hbuf, n);
  k_agg<<<(n + 3) / 4, 256, 0, stream>>>(hbuf, csr, offs, dinv, b2, habuf, n);

  k_pool<<<G, 128, 0, stream>>>(habuf, bat, pooled, n, G);
  k_head<<<G, 128, 0, stream>>>(pooled, axd, l1W, l1b, axW, axb, l2W, l2b, out, G);
}

// Round 2
// 334.915 us; speedup vs baseline: 1.4244x; 1.4244x over previous
//
#include <hip/hip_runtime.h>

// patient_GCN: 2x GCNConv(128->128) + mean-pool + head.
// R2: bf16 MFMA GEMM (16x16x32, W^T staged in LDS) + bf16 gather aggregation.
// fp32 accumulation everywhere; bf16 only as storage + MFMA inputs.

#define NFEAT 128

typedef __attribute__((ext_vector_type(8))) short bf16x8;
typedef __attribute__((ext_vector_type(4))) float f32x4;

static __device__ __forceinline__ unsigned short f2bf(float f) {
  // round-to-nearest-even fp32 -> bf16 (finite inputs)
  unsigned u = __float_as_uint(f);
  return (unsigned short)((u + 0x7fffu + ((u >> 16) & 1u)) >> 16);
}
static __device__ __forceinline__ float bf_lo(unsigned u) { return __uint_as_float(u << 16); }
static __device__ __forceinline__ float bf_hi(unsigned u) { return __uint_as_float(u & 0xffff0000u); }

// ---------------- CSR build ----------------
__global__ void k_deg(const int* __restrict__ dst, int* __restrict__ cnt, int E) {
  int e = blockIdx.x * 256 + threadIdx.x;
  if (e < E) atomicAdd(&cnt[dst[e]], 1);
}

__global__ void k_part(const int* __restrict__ cnt, int* __restrict__ part, int n) {
  __shared__ int s[256];
  int t = threadIdx.x;
  int idx = blockIdx.x * 256 + t;
  s[t] = (idx < n) ? cnt[idx] : 0;
  __syncthreads();
  for (int o = 128; o > 0; o >>= 1) {
    if (t < o) s[t] += s[t + o];
    __syncthreads();
  }
  if (t == 0) part[blockIdx.x] = s[0];
}

__global__ void k_scan1(const int* __restrict__ part, int* __restrict__ ppre,
                        int NB, int* __restrict__ offs, int n) {
  __shared__ int s[256];
  int t = threadIdx.x;
  int v = (t < NB) ? part[t] : 0;
  s[t] = v;
  __syncthreads();
  for (int o = 1; o < 256; o <<= 1) {
    int tmp = (t >= o) ? s[t - o] : 0;
    __syncthreads();
    s[t] += tmp;
    __syncthreads();
  }
  if (t < NB) ppre[t] = s[t] - v;
  if (t == NB - 1) offs[n] = s[t];
}

__global__ void k_offsets(const int* __restrict__ cnt, const int* __restrict__ ppre,
                          int* __restrict__ offs, int* __restrict__ cursor, int n) {
  __shared__ int s[256];
  int t = threadIdx.x;
  int idx = blockIdx.x * 256 + t;
  int v = (idx < n) ? cnt[idx] : 0;
  s[t] = v;
  __syncthreads();
  for (int o = 1; o < 256; o <<= 1) {
    int tmp = (t >= o) ? s[t - o] : 0;
    __syncthreads();
    s[t] += tmp;
    __syncthreads();
  }
  if (idx < n) {
    int off = ppre[blockIdx.x] + s[t] - v;
    offs[idx] = off;
    cursor[idx] = off;
  }
}

__global__ void k_fill(const int* __restrict__ src, const int* __restrict__ dst,
                       int* __restrict__ cursor, int* __restrict__ csr, int E) {
  int e = blockIdx.x * 256 + threadIdx.x;
  if (e < E) {
    int p = atomicAdd(&cursor[dst[e]], 1);
    csr[p] = src[e];
  }
}

__global__ void k_dinv(const int* __restrict__ cnt, float* __restrict__ dinv, int n) {
  int i = blockIdx.x * 256 + threadIdx.x;
  if (i < n) dinv[i] = rsqrtf((float)(cnt[i] + 1));
}

// ---------------- W prep: W[k][n] fp32 -> WT[n][k] bf16 ----------------
__global__ void k_wprep(const float* __restrict__ W, unsigned short* __restrict__ WT) {
  int n = blockIdx.x, k = threadIdx.x;  // 128 x 128
  WT[n * 128 + k] = f2bf(W[k * 128 + n]);
}

// ---------------- GEMM: H[M,128](bf16) = X[M,128] @ W[128,128] ----------------
// 16x16x32 bf16 MFMA. Whole W^T in LDS (padded stride 136 -> conflict-free
// b128 fragment reads). BM=64, 4 waves, wave w covers rows w*16..w*16+15,
// loops 8 n-tiles x 4 k-chunks. Single K pass (K=128 fully staged).
template <bool FP32IN>
__global__ __launch_bounds__(256) void k_gemm_mfma(const void* __restrict__ Xv,
                                                   const uint4* __restrict__ WT4,
                                                   unsigned short* __restrict__ H,
                                                   int M) {
  __shared__ __align__(16) unsigned short sW[128 * 136];
  __shared__ __align__(16) unsigned short sX[64 * 136];
  int tid = threadIdx.x;
  int m0 = blockIdx.x * 64;

  // stage W^T bf16 [n][k] -> sW[n*136+k], 2048 uint4, coalesced
#pragma unroll
  for (int t = 0; t < 8; t++) {
    int idx = tid + t * 256;
    int n = idx >> 4, c8 = idx & 15;
    *(uint4*)(sW + n * 136 + c8 * 8) = WT4[idx];
  }
  // stage X tile rows m0..m0+63 -> sX[r*136+k] (bf16)
  if (FP32IN) {
    const float4* X4 = (const float4*)Xv;
#pragma unroll
    for (int t = 0; t < 8; t++) {
      int idx = tid + t * 256;         // 2048 float4
      int r = idx >> 5, c4 = idx & 31;
      int m = m0 + r;
      float4 v = make_float4(0.f, 0.f, 0.f, 0.f);
      if (m < M) v = X4[(size_t)m * 32 + c4];
      unsigned short* p = sX + r * 136 + c4 * 4;
      ushort2 lo, hi;
      lo.x = f2bf(v.x); lo.y = f2bf(v.y);
      hi.x = f2bf(v.z); hi.y = f2bf(v.w);
      *(ushort2*)(p) = lo;
      *(ushort2*)(p + 2) = hi;
    }
  } else {
    const uint4* X4 = (const uint4*)Xv;
#pragma unroll
    for (int t = 0; t < 4; t++) {
      int idx = tid + t * 256;         // 1024 uint4
      int r = idx >> 4, c8 = idx & 15;
      int m = m0 + r;
      uint4 v = make_uint4(0u, 0u, 0u, 0u);
      if (m < M) v = X4[(size_t)m * 16 + c8];
      *(uint4*)(sX + r * 136 + c8 * 8) = v;
    }
  }
  __syncthreads();

  int lane = tid & 63, wv = tid >> 6;
  int ln15 = lane & 15, q = lane >> 4;
  bf16x8 afrag[4];
#pragma unroll
  for (int c = 0; c < 4; c++)
    afrag[c] = *(const bf16x8*)(sX + (wv * 16 + ln15) * 136 + c * 32 + q * 8);

  int r0 = m0 + wv * 16 + q * 4;  // C/D rows base: row = q*4 + reg
#pragma unroll
  for (int j = 0; j < 8; j++) {
    f32x4 acc = {0.f, 0.f, 0.f, 0.f};
#pragma unroll
    for (int c = 0; c < 4; c++) {
      bf16x8 bfrag = *(const bf16x8*)(sW + (j * 16 + ln15) * 136 + c * 32 + q * 8);
      acc = __builtin_amdgcn_mfma_f32_16x16x32_bf16(afrag[c], bfrag, acc, 0, 0, 0);
    }
    int col = j * 16 + ln15;
#pragma unroll
    for (int rr = 0; rr < 4; rr++) {
      int m = r0 + rr;
      if (m < M) H[(size_t)m * 128 + col] = f2bf(acc[rr]);
    }
  }
}

// ---------------- Aggregation (bf16 rows): one wave/node, lane = bf16 pair --------
// out[i] = relu(b + dinv[i]*sum_in dinv[s]*h[s] + dinv[i]^2*h[i])
__global__ __launch_bounds__(256) void k_agg(const unsigned* __restrict__ H2,
                                             const int* __restrict__ csr,
                                             const int* __restrict__ offs,
                                             const float* __restrict__ dinv,
                                             const float* __restrict__ bias,
                                             unsigned* __restrict__ Ho, int n) {
  int lane = threadIdx.x & 63;
  int i = blockIdx.x * 4 + (threadIdx.x >> 6);
  if (i >= n) return;
  float di = dinv[i];
  unsigned sv = H2[(size_t)i * 64 + lane];
  int e0 = offs[i], e1 = offs[i + 1];
  float ax = 0.f, ay = 0.f;
  int e = e0;
  for (; e + 1 < e1; e += 2) {
    int s0 = csr[e], s1 = csr[e + 1];
    float d0 = dinv[s0], d1 = dinv[s1];
    unsigned h0 = H2[(size_t)s0 * 64 + lane];
    unsigned h1 = H2[(size_t)s1 * 64 + lane];
    ax += d0 * bf_lo(h0) + d1 * bf_lo(h1);
    ay += d0 * bf_hi(h0) + d1 * bf_hi(h1);
  }
  if (e < e1) {
    int s0 = csr[e];
    float d0 = dinv[s0];
    unsigned h0 = H2[(size_t)s0 * 64 + lane];
    ax += d0 * bf_lo(h0);
    ay += d0 * bf_hi(h0);
  }
  float2 b = ((const float2*)bias)[lane];
  float ox = b.x + di * ax + di * di * bf_lo(sv);
  float oy = b.y + di * ay + di * di * bf_hi(sv);
  ox = fmaxf(ox, 0.f);
  oy = fmaxf(oy, 0.f);
  Ho[(size_t)i * 64 + lane] = (unsigned)f2bf(ox) | ((unsigned)f2bf(oy) << 16);
}

// ---------------- Mean pool over sorted batch (bf16 in, fp32 out) --------------
__global__ void k_pool(const unsigned short* __restrict__ Hb, const int* __restrict__ batch,
                       float* __restrict__ pooled, int n, int G) {
  int g = blockIdx.x, t = threadIdx.x;  // 128 threads
  __shared__ int sb[2];
  if (t < 2) {
    int target = g + t;
    int lo = 0, hi = n;
    while (lo < hi) {
      int mid = (lo + hi) >> 1;
      if (batch[mid] < target) lo = mid + 1; else hi = mid;
    }
    sb[t] = lo;
  }
  __syncthreads();
  int s = sb[0], epos = sb[1];
  float sum = 0.f;
  for (int r = s; r < epos; r++)
    sum += __uint_as_float(((unsigned)Hb[(size_t)r * 128 + t]) << 16);
  int c = epos - s;
  if (c < 1) c = 1;
  pooled[g * 128 + t] = sum / (float)c;
}

// ---------------- Head ----------------
__global__ void k_head(const float* __restrict__ pooled, const float* __restrict__ axd,
                       const float* __restrict__ l1W, const float* __restrict__ l1b,
                       const float* __restrict__ axW, const float* __restrict__ axb,
                       const float* __restrict__ l2W, const float* __restrict__ l2b,
                       float* __restrict__ out, int G) {
  int g = blockIdx.x, t = threadIdx.x;  // 128 threads
  __shared__ float z[192];
  __shared__ float p[128];
  __shared__ float a[64];
  p[t] = pooled[g * 128 + t];
  if (t < 64) a[t] = axd[g * 64 + t];
  __syncthreads();
  float accg = l1b[t];
  for (int k = 0; k < 128; k++) accg += p[k] * l1W[k * 128 + t];
  z[t] = accg;
  if (t < 64) {
    float acca = axb[t];
    for (int k = 0; k < 64; k++) acca += a[k] * axW[k * 64 + t];
    z[128 + t] = acca;
  }
  __syncthreads();
  if (t < 8) {
    float acc = l2b[t];
    for (int k = 0; k < 192; k++) acc += z[k] * l2W[k * 8 + t];
    out[g * 8 + t] = acc;
  }
}

extern "C" void kernel_launch(void* const* d_in, const int* in_sizes, int n_in,
                              void* d_out, int out_size, void* d_ws, size_t ws_size,
                              hipStream_t stream) {
  const float* x   = (const float*)d_in[0];
  const int*   ei  = (const int*)d_in[1];
  const int*   bat = (const int*)d_in[2];
  const float* axd = (const float*)d_in[3];
  const float* W1  = (const float*)d_in[4];
  const float* b1  = (const float*)d_in[5];
  const float* W2  = (const float*)d_in[6];
  const float* b2  = (const float*)d_in[7];
  const float* l1W = (const float*)d_in[8];
  const float* l1b = (const float*)d_in[9];
  const float* axW = (const float*)d_in[10];
  const float* axb = (const float*)d_in[11];
  const float* l2W = (const float*)d_in[12];
  const float* l2b = (const float*)d_in[13];
  float* out = (float*)d_out;

  int n = in_sizes[0] / NFEAT;   // 50000
  int E = in_sizes[1] / 2;       // 640000
  int G = in_sizes[3] / 64;      // 512

  // workspace layout
  unsigned short* hbuf  = (unsigned short*)d_ws;           // n*128 bf16
  unsigned short* habuf = hbuf + (size_t)n * NFEAT;        // n*128 bf16
  unsigned short* wt1   = habuf + (size_t)n * NFEAT;       // 16384 bf16
  unsigned short* wt2   = wt1 + 16384;                     // 16384 bf16
  int*   csr    = (int*)(wt2 + 16384);                     // E
  int*   offs   = csr + E;                                 // n+1
  int*   cursor = offs + (n + 1);                          // n
  int*   cnt    = cursor + n;                              // n
  float* dinv   = (float*)(cnt + n);                       // n
  int*   part   = (int*)(dinv + n);                        // 256
  int*   ppre   = part + 256;                              // 256
  float* pooled = (float*)(ppre + 256);                    // G*128

  const int* srcv = ei;
  const int* dstv = ei + E;
  int NB = (n + 255) / 256;

  hipMemsetAsync(cnt, 0, (size_t)n * sizeof(int), stream);
  k_deg<<<(E + 255) / 256, 256, 0, stream>>>(dstv, cnt, E);
  k_part<<<NB, 256, 0, stream>>>(cnt, part, n);
  k_scan1<<<1, 256, 0, stream>>>(part, ppre, NB, offs, n);
  k_offsets<<<NB, 256, 0, stream>>>(cnt, ppre, offs, cursor, n);
  k_fill<<<(E + 255) / 256, 256, 0, stream>>>(srcv, dstv, cursor, csr, E);
  k_dinv<<<(n + 255) / 256, 256, 0, stream>>>(cnt, dinv, n);
  k_wprep<<<128, 128, 0, stream>>>(W1, wt1);
  k_wprep<<<128, 128, 0, stream>>>(W2, wt2);

  int gb = (n + 63) / 64;
  k_gemm_mfma<true><<<gb, 256, 0, stream>>>(x, (const uint4*)wt1, hbuf, n);
  k_agg<<<(n + 3) / 4, 256, 0, stream>>>((const unsigned*)hbuf, csr, offs, dinv, b1,
                                         (unsigned*)habuf, n);
  k_gemm_mfma<false><<<gb, 256, 0, stream>>>(habuf, (const uint4*)wt2, hbuf, n);
  k_agg<<<(n + 3) / 4, 256, 0, stream>>>((const unsigned*)hbuf, csr, offs, dinv, b2,
                                         (unsigned*)habuf, n);

  k_pool<<<G, 128, 0, stream>>>(habuf, bat, pooled, n, G);
  k_head<<<G, 128, 0, stream>>>(pooled, axd, l1W, l1b, axW, axb, l2W, l2b, out, G);
}

// Round 3
// 317.464 us; speedup vs baseline: 1.5027x; 1.0550x over previous
//
#include <hip/hip_runtime.h>

// patient_GCN: 2x GCNConv(128->128) + mean-pool + head.
// R3: dinv folded into GEMM epilogue (agg inner loop = load+add only),
// unroll-4 gather ILP, fused dinv/wprep/pool+head kernels.

#define NFEAT 128

typedef __attribute__((ext_vector_type(8))) short bf16x8;
typedef __attribute__((ext_vector_type(4))) float f32x4;

static __device__ __forceinline__ unsigned short f2bf(float f) {
  unsigned u = __float_as_uint(f);
  return (unsigned short)((u + 0x7fffu + ((u >> 16) & 1u)) >> 16);
}
static __device__ __forceinline__ float bf_lo(unsigned u) { return __uint_as_float(u << 16); }
static __device__ __forceinline__ float bf_hi(unsigned u) { return __uint_as_float(u & 0xffff0000u); }

// ---------------- CSR build ----------------
__global__ void k_deg(const int* __restrict__ dst, int* __restrict__ cnt, int E) {
  int e = blockIdx.x * 256 + threadIdx.x;
  if (e < E) atomicAdd(&cnt[dst[e]], 1);
}

__global__ void k_part(const int* __restrict__ cnt, int* __restrict__ part, int n) {
  __shared__ int s[256];
  int t = threadIdx.x;
  int idx = blockIdx.x * 256 + t;
  s[t] = (idx < n) ? cnt[idx] : 0;
  __syncthreads();
  for (int o = 128; o > 0; o >>= 1) {
    if (t < o) s[t] += s[t + o];
    __syncthreads();
  }
  if (t == 0) part[blockIdx.x] = s[0];
}

__global__ void k_scan1(const int* __restrict__ part, int* __restrict__ ppre,
                        int NB, int* __restrict__ offs, int n) {
  __shared__ int s[256];
  int t = threadIdx.x;
  int v = (t < NB) ? part[t] : 0;
  s[t] = v;
  __syncthreads();
  for (int o = 1; o < 256; o <<= 1) {
    int tmp = (t >= o) ? s[t - o] : 0;
    __syncthreads();
    s[t] += tmp;
    __syncthreads();
  }
  if (t < NB) ppre[t] = s[t] - v;
  if (t == NB - 1) offs[n] = s[t];
}

// offsets + cursor + dinv in one pass
__global__ void k_offsets(const int* __restrict__ cnt, const int* __restrict__ ppre,
                          int* __restrict__ offs, int* __restrict__ cursor,
                          float* __restrict__ dinv, int n) {
  __shared__ int s[256];
  int t = threadIdx.x;
  int idx = blockIdx.x * 256 + t;
  int v = (idx < n) ? cnt[idx] : 0;
  s[t] = v;
  __syncthreads();
  for (int o = 1; o < 256; o <<= 1) {
    int tmp = (t >= o) ? s[t - o] : 0;
    __syncthreads();
    s[t] += tmp;
    __syncthreads();
  }
  if (idx < n) {
    int off = ppre[blockIdx.x] + s[t] - v;
    offs[idx] = off;
    cursor[idx] = off;
    dinv[idx] = rsqrtf((float)(v + 1));
  }
}

__global__ void k_fill(const int* __restrict__ src, const int* __restrict__ dst,
                       int* __restrict__ cursor, int* __restrict__ csr, int E) {
  int e = blockIdx.x * 256 + threadIdx.x;
  if (e < E) {
    int p = atomicAdd(&cursor[dst[e]], 1);
    csr[p] = src[e];
  }
}

// ---------------- W prep: both weights, W[k][n] fp32 -> WT[n][k] bf16 --------
__global__ void k_wprep(const float* __restrict__ W1, const float* __restrict__ W2,
                        unsigned short* __restrict__ WT1, unsigned short* __restrict__ WT2) {
  int b = blockIdx.x, k = threadIdx.x;  // 256 x 128
  if (b < 128) WT1[b * 128 + k] = f2bf(W1[k * 128 + b]);
  else { int nn = b - 128; WT2[nn * 128 + k] = f2bf(W2[k * 128 + nn]); }
}

// ---------------- GEMM: Hs[M,128](bf16) = dinv[m] * (X[M,128] @ W) ----------------
template <bool FP32IN>
__global__ __launch_bounds__(256) void k_gemm_mfma(const void* __restrict__ Xv,
                                                   const uint4* __restrict__ WT4,
                                                   const float* __restrict__ dinv,
                                                   unsigned short* __restrict__ H,
                                                   int M) {
  __shared__ __align__(16) unsigned short sW[128 * 136];
  __shared__ __align__(16) unsigned short sX[64 * 136];
  int tid = threadIdx.x;
  int m0 = blockIdx.x * 64;

#pragma unroll
  for (int t = 0; t < 8; t++) {
    int idx = tid + t * 256;
    int n = idx >> 4, c8 = idx & 15;
    *(uint4*)(sW + n * 136 + c8 * 8) = WT4[idx];
  }
  if (FP32IN) {
    const float4* X4 = (const float4*)Xv;
#pragma unroll
    for (int t = 0; t < 8; t++) {
      int idx = tid + t * 256;
      int r = idx >> 5, c4 = idx & 31;
      int m = m0 + r;
      float4 v = make_float4(0.f, 0.f, 0.f, 0.f);
      if (m < M) v = X4[(size_t)m * 32 + c4];
      unsigned short* p = sX + r * 136 + c4 * 4;
      ushort2 lo, hi;
      lo.x = f2bf(v.x); lo.y = f2bf(v.y);
      hi.x = f2bf(v.z); hi.y = f2bf(v.w);
      *(ushort2*)(p) = lo;
      *(ushort2*)(p + 2) = hi;
    }
  } else {
    const uint4* X4 = (const uint4*)Xv;
#pragma unroll
    for (int t = 0; t < 4; t++) {
      int idx = tid + t * 256;
      int r = idx >> 4, c8 = idx & 15;
      int m = m0 + r;
      uint4 v = make_uint4(0u, 0u, 0u, 0u);
      if (m < M) v = X4[(size_t)m * 16 + c8];
      *(uint4*)(sX + r * 136 + c8 * 8) = v;
    }
  }
  __syncthreads();

  int lane = tid & 63, wv = tid >> 6;
  int ln15 = lane & 15, q = lane >> 4;
  bf16x8 afrag[4];
#pragma unroll
  for (int c = 0; c < 4; c++)
    afrag[c] = *(const bf16x8*)(sX + (wv * 16 + ln15) * 136 + c * 32 + q * 8);

  int r0 = m0 + wv * 16 + q * 4;
  float dv[4];
#pragma unroll
  for (int rr = 0; rr < 4; rr++) dv[rr] = (r0 + rr < M) ? dinv[r0 + rr] : 0.f;

#pragma unroll
  for (int j = 0; j < 8; j++) {
    f32x4 acc = {0.f, 0.f, 0.f, 0.f};
#pragma unroll
    for (int c = 0; c < 4; c++) {
      bf16x8 bfrag = *(const bf16x8*)(sW + (j * 16 + ln15) * 136 + c * 32 + q * 8);
      acc = __builtin_amdgcn_mfma_f32_16x16x32_bf16(afrag[c], bfrag, acc, 0, 0, 0);
    }
    int col = j * 16 + ln15;
#pragma unroll
    for (int rr = 0; rr < 4; rr++) {
      int m = r0 + rr;
      if (m < M) H[(size_t)m * 128 + col] = f2bf(dv[rr] * acc[rr]);
    }
  }
}

// ---------------- Aggregation: rows prescaled; inner loop = load + add --------
// out[i] = relu(b + dinv[i]*(Hs[i] + sum_{s in N(i)} Hs[s]))
__global__ __launch_bounds__(256) void k_agg(const unsigned* __restrict__ H2,
                                             const int* __restrict__ csr,
                                             const int* __restrict__ offs,
                                             const float* __restrict__ dinv,
                                             const float* __restrict__ bias,
                                             unsigned* __restrict__ Ho, int n) {
  int lane = threadIdx.x & 63;
  int i = blockIdx.x * 4 + (threadIdx.x >> 6);
  if (i >= n) return;
  unsigned sv = H2[(size_t)i * 64 + lane];
  float ax = bf_lo(sv), ay = bf_hi(sv);
  int e0 = offs[i], e1 = offs[i + 1];
  int e = e0;
  for (; e + 4 <= e1; e += 4) {
    int s0 = csr[e], s1 = csr[e + 1], s2 = csr[e + 2], s3 = csr[e + 3];
    unsigned h0 = H2[(size_t)s0 * 64 + lane];
    unsigned h1 = H2[(size_t)s1 * 64 + lane];
    unsigned h2 = H2[(size_t)s2 * 64 + lane];
    unsigned h3 = H2[(size_t)s3 * 64 + lane];
    ax += bf_lo(h0) + bf_lo(h1) + bf_lo(h2) + bf_lo(h3);
    ay += bf_hi(h0) + bf_hi(h1) + bf_hi(h2) + bf_hi(h3);
  }
  for (; e < e1; e++) {
    unsigned h0 = H2[(size_t)csr[e] * 64 + lane];
    ax += bf_lo(h0);
    ay += bf_hi(h0);
  }
  float di = dinv[i];
  float2 b = ((const float2*)bias)[lane];
  float ox = fmaxf(b.x + di * ax, 0.f);
  float oy = fmaxf(b.y + di * ay, 0.f);
  Ho[(size_t)i * 64 + lane] = (unsigned)f2bf(ox) | ((unsigned)f2bf(oy) << 16);
}

// ---------------- Fused mean-pool (sorted batch) + head ----------------
__global__ void k_poolhead(const unsigned short* __restrict__ Hb,
                           const int* __restrict__ batch, const float* __restrict__ axd,
                           const float* __restrict__ l1W, const float* __restrict__ l1b,
                           const float* __restrict__ axW, const float* __restrict__ axb,
                           const float* __restrict__ l2W, const float* __restrict__ l2b,
                           float* __restrict__ out, int n) {
  int g = blockIdx.x, t = threadIdx.x;  // 128 threads
  __shared__ int sb[2];
  if (t < 2) {
    int target = g + t;
    int lo = 0, hi = n;
    while (lo < hi) {
      int mid = (lo + hi) >> 1;
      if (batch[mid] < target) lo = mid + 1; else hi = mid;
    }
    sb[t] = lo;
  }
  __syncthreads();
  int s = sb[0], epos = sb[1];
  float sum = 0.f;
  for (int r = s; r < epos; r++)
    sum += __uint_as_float(((unsigned)Hb[(size_t)r * 128 + t]) << 16);
  int c = epos - s;
  if (c < 1) c = 1;
  __shared__ float p[128];
  __shared__ float z[192];
  __shared__ float a[64];
  p[t] = sum / (float)c;
  if (t < 64) a[t] = axd[g * 64 + t];
  __syncthreads();
  float accg = l1b[t];
  for (int k = 0; k < 128; k++) accg += p[k] * l1W[k * 128 + t];
  z[t] = accg;
  if (t < 64) {
    float acca = axb[t];
    for (int k = 0; k < 64; k++) acca += a[k] * axW[k * 64 + t];
    z[128 + t] = acca;
  }
  __syncthreads();
  if (t < 8) {
    float acc = l2b[t];
    for (int k = 0; k < 192; k++) acc += z[k] * l2W[k * 8 + t];
    out[g * 8 + t] = acc;
  }
}

extern "C" void kernel_launch(void* const* d_in, const int* in_sizes, int n_in,
                              void* d_out, int out_size, void* d_ws, size_t ws_size,
                              hipStream_t stream) {
  const float* x   = (const float*)d_in[0];
  const int*   ei  = (const int*)d_in[1];
  const int*   bat = (const int*)d_in[2];
  const float* axd = (const float*)d_in[3];
  const float* W1  = (const float*)d_in[4];
  const float* b1  = (const float*)d_in[5];
  const float* W2  = (const float*)d_in[6];
  const float* b2  = (const float*)d_in[7];
  const float* l1W = (const float*)d_in[8];
  const float* l1b = (const float*)d_in[9];
  const float* axW = (const float*)d_in[10];
  const float* axb = (const float*)d_in[11];
  const float* l2W = (const float*)d_in[12];
  const float* l2b = (const float*)d_in[13];
  float* out = (float*)d_out;

  int n = in_sizes[0] / NFEAT;   // 50000
  int E = in_sizes[1] / 2;       // 640000
  int G = in_sizes[3] / 64;      // 512

  unsigned short* hbuf  = (unsigned short*)d_ws;           // n*128 bf16
  unsigned short* habuf = hbuf + (size_t)n * NFEAT;        // n*128 bf16
  unsigned short* wt1   = habuf + (size_t)n * NFEAT;       // 16384 bf16
  unsigned short* wt2   = wt1 + 16384;                     // 16384 bf16
  int*   csr    = (int*)(wt2 + 16384);                     // E
  int*   offs   = csr + E;                                 // n+1
  int*   cursor = offs + (n + 1);                          // n
  int*   cnt    = cursor + n;                              // n
  float* dinv   = (float*)(cnt + n);                       // n
  int*   part   = (int*)(dinv + n);                        // 256
  int*   ppre   = part + 256;                              // 256

  const int* srcv = ei;
  const int* dstv = ei + E;
  int NB = (n + 255) / 256;

  hipMemsetAsync(cnt, 0, (size_t)n * sizeof(int), stream);
  k_deg<<<(E + 255) / 256, 256, 0, stream>>>(dstv, cnt, E);
  k_part<<<NB, 256, 0, stream>>>(cnt, part, n);
  k_scan1<<<1, 256, 0, stream>>>(part, ppre, NB, offs, n);
  k_offsets<<<NB, 256, 0, stream>>>(cnt, ppre, offs, cursor, dinv, n);
  k_fill<<<(E + 255) / 256, 256, 0, stream>>>(srcv, dstv, cursor, csr, E);
  k_wprep<<<256, 128, 0, stream>>>(W1, W2, wt1, wt2);

  int gb = (n + 63) / 64;
  k_gemm_mfma<true><<<gb, 256, 0, stream>>>(x, (const uint4*)wt1, dinv, hbuf, n);
  k_agg<<<(n + 3) / 4, 256, 0, stream>>>((const unsigned*)hbuf, csr, offs, dinv, b1,
                                         (unsigned*)habuf, n);
  k_gemm_mfma<false><<<gb, 256, 0, stream>>>(habuf, (const uint4*)wt2, dinv, hbuf, n);
  k_agg<<<(n + 3) / 4, 256, 0, stream>>>((const unsigned*)hbuf, csr, offs, dinv, b2,
                                         (unsigned*)habuf, n);

  k_poolhead<<<G, 128, 0, stream>>>(habuf, bat, axd, l1W, l1b, axW, axb, l2W, l2b, out, n);
}

// Round 4
// 306.831 us; speedup vs baseline: 1.5548x; 1.0347x over previous
//
#include <hip/hip_runtime.h>

// patient_GCN: 2x GCNConv(128->128) + mean-pool + head.
// R4: agg processes 4 edges/wave (uint4 quarter-wave rows, 8 rows in flight);
// pool = node-parallel atomic segmented sum; head = own 192-thread kernel.

#define NFEAT 128
#define NPB 128  // nodes per pool block

typedef __attribute__((ext_vector_type(8))) short bf16x8;
typedef __attribute__((ext_vector_type(4))) float f32x4;

static __device__ __forceinline__ unsigned short f2bf(float f) {
  unsigned u = __float_as_uint(f);
  return (unsigned short)((u + 0x7fffu + ((u >> 16) & 1u)) >> 16);
}
static __device__ __forceinline__ unsigned pack2(float a, float b) {
  return (unsigned)f2bf(a) | ((unsigned)f2bf(b) << 16);
}
static __device__ __forceinline__ float bf_lo(unsigned u) { return __uint_as_float(u << 16); }
static __device__ __forceinline__ float bf_hi(unsigned u) { return __uint_as_float(u & 0xffff0000u); }

// ---------------- CSR build ----------------
__global__ void k_deg(const int* __restrict__ dst, int* __restrict__ cnt, int E) {
  int e = blockIdx.x * 256 + threadIdx.x;
  if (e < E) atomicAdd(&cnt[dst[e]], 1);
}

__global__ void k_part(const int* __restrict__ cnt, int* __restrict__ part, int n) {
  __shared__ int s[256];
  int t = threadIdx.x;
  int idx = blockIdx.x * 256 + t;
  s[t] = (idx < n) ? cnt[idx] : 0;
  __syncthreads();
  for (int o = 128; o > 0; o >>= 1) {
    if (t < o) s[t] += s[t + o];
    __syncthreads();
  }
  if (t == 0) part[blockIdx.x] = s[0];
}

__global__ void k_scan1(const int* __restrict__ part, int* __restrict__ ppre,
                        int NB, int* __restrict__ offs, int n) {
  __shared__ int s[256];
  int t = threadIdx.x;
  int v = (t < NB) ? part[t] : 0;
  s[t] = v;
  __syncthreads();
  for (int o = 1; o < 256; o <<= 1) {
    int tmp = (t >= o) ? s[t - o] : 0;
    __syncthreads();
    s[t] += tmp;
    __syncthreads();
  }
  if (t < NB) ppre[t] = s[t] - v;
  if (t == NB - 1) offs[n] = s[t];
}

__global__ void k_offsets(const int* __restrict__ cnt, const int* __restrict__ ppre,
                          int* __restrict__ offs, int* __restrict__ cursor,
                          float* __restrict__ dinv, int n) {
  __shared__ int s[256];
  int t = threadIdx.x;
  int idx = blockIdx.x * 256 + t;
  int v = (idx < n) ? cnt[idx] : 0;
  s[t] = v;
  __syncthreads();
  for (int o = 1; o < 256; o <<= 1) {
    int tmp = (t >= o) ? s[t - o] : 0;
    __syncthreads();
    s[t] += tmp;
    __syncthreads();
  }
  if (idx < n) {
    int off = ppre[blockIdx.x] + s[t] - v;
    offs[idx] = off;
    cursor[idx] = off;
    dinv[idx] = rsqrtf((float)(v + 1));
  }
}

__global__ void k_fill(const int* __restrict__ src, const int* __restrict__ dst,
                       int* __restrict__ cursor, int* __restrict__ csr, int E) {
  int e = blockIdx.x * 256 + threadIdx.x;
  if (e < E) {
    int p = atomicAdd(&cursor[dst[e]], 1);
    csr[p] = src[e];
  }
}

// graph boundaries from sorted batch: gstart[g], gstart[G]=n
__global__ void k_gbounds(const int* __restrict__ batch, int* __restrict__ gstart,
                          int n, int G) {
  int g = threadIdx.x;
  if (g > G) return;
  if (g == G) { gstart[g] = n; return; }
  int lo = 0, hi = n;
  while (lo < hi) {
    int mid = (lo + hi) >> 1;
    if (batch[mid] < g) lo = mid + 1; else hi = mid;
  }
  gstart[g] = lo;
}

// ---------------- W prep ----------------
__global__ void k_wprep(const float* __restrict__ W1, const float* __restrict__ W2,
                        unsigned short* __restrict__ WT1, unsigned short* __restrict__ WT2) {
  int b = blockIdx.x, k = threadIdx.x;
  if (b < 128) WT1[b * 128 + k] = f2bf(W1[k * 128 + b]);
  else { int nn = b - 128; WT2[nn * 128 + k] = f2bf(W2[k * 128 + nn]); }
}

// ---------------- GEMM: Hs[M,128](bf16) = dinv[m] * (X[M,128] @ W) ----------------
template <bool FP32IN>
__global__ __launch_bounds__(256) void k_gemm_mfma(const void* __restrict__ Xv,
                                                   const uint4* __restrict__ WT4,
                                                   const float* __restrict__ dinv,
                                                   unsigned short* __restrict__ H,
                                                   int M) {
  __shared__ __align__(16) unsigned short sW[128 * 136];
  __shared__ __align__(16) unsigned short sX[64 * 136];
  int tid = threadIdx.x;
  int m0 = blockIdx.x * 64;

#pragma unroll
  for (int t = 0; t < 8; t++) {
    int idx = tid + t * 256;
    int n = idx >> 4, c8 = idx & 15;
    *(uint4*)(sW + n * 136 + c8 * 8) = WT4[idx];
  }
  if (FP32IN) {
    const float4* X4 = (const float4*)Xv;
#pragma unroll
    for (int t = 0; t < 8; t++) {
      int idx = tid + t * 256;
      int r = idx >> 5, c4 = idx & 31;
      int m = m0 + r;
      float4 v = make_float4(0.f, 0.f, 0.f, 0.f);
      if (m < M) v = X4[(size_t)m * 32 + c4];
      unsigned short* p = sX + r * 136 + c4 * 4;
      *(ushort2*)(p) = make_ushort2(f2bf(v.x), f2bf(v.y));
      *(ushort2*)(p + 2) = make_ushort2(f2bf(v.z), f2bf(v.w));
    }
  } else {
    const uint4* X4 = (const uint4*)Xv;
#pragma unroll
    for (int t = 0; t < 4; t++) {
      int idx = tid + t * 256;
      int r = idx >> 4, c8 = idx & 15;
      int m = m0 + r;
      uint4 v = make_uint4(0u, 0u, 0u, 0u);
      if (m < M) v = X4[(size_t)m * 16 + c8];
      *(uint4*)(sX + r * 136 + c8 * 8) = v;
    }
  }
  __syncthreads();

  int lane = tid & 63, wv = tid >> 6;
  int ln15 = lane & 15, q = lane >> 4;
  bf16x8 afrag[4];
#pragma unroll
  for (int c = 0; c < 4; c++)
    afrag[c] = *(const bf16x8*)(sX + (wv * 16 + ln15) * 136 + c * 32 + q * 8);

  int r0 = m0 + wv * 16 + q * 4;
  float dv[4];
#pragma unroll
  for (int rr = 0; rr < 4; rr++) dv[rr] = (r0 + rr < M) ? dinv[r0 + rr] : 0.f;

#pragma unroll
  for (int j = 0; j < 8; j++) {
    f32x4 acc = {0.f, 0.f, 0.f, 0.f};
#pragma unroll
    for (int c = 0; c < 4; c++) {
      bf16x8 bfrag = *(const bf16x8*)(sW + (j * 16 + ln15) * 136 + c * 32 + q * 8);
      acc = __builtin_amdgcn_mfma_f32_16x16x32_bf16(afrag[c], bfrag, acc, 0, 0, 0);
    }
    int col = j * 16 + ln15;
#pragma unroll
    for (int rr = 0; rr < 4; rr++) {
      int m = r0 + rr;
      if (m < M) H[(size_t)m * 128 + col] = f2bf(dv[rr] * acc[rr]);
    }
  }
}

// ---------------- Aggregation: 1 wave/node, 4 edges per pass ----------------
// quarter q = lane>>4 handles edge e+q; k = lane&15 covers 16B (8 feats).
// out[i] = relu(b + dinv[i]*(Hs[i] + sum_{s in N(i)} Hs[s]))
__global__ __launch_bounds__(256) void k_agg(const uint4* __restrict__ H4,
                                             const int* __restrict__ csr,
                                             const int* __restrict__ offs,
                                             const float* __restrict__ dinv,
                                             const float* __restrict__ bias,
                                             uint4* __restrict__ Ho, int n) {
  int lane = threadIdx.x & 63;
  int i = blockIdx.x * 4 + (threadIdx.x >> 6);
  if (i >= n) return;
  int q = lane >> 4, k = lane & 15;
  float a0 = 0.f, a1 = 0.f, a2 = 0.f, a3 = 0.f, a4 = 0.f, a5 = 0.f, a6 = 0.f, a7 = 0.f;
  if (q == 0) {  // self row
    uint4 sv = H4[(size_t)i * 16 + k];
    a0 = bf_lo(sv.x); a1 = bf_hi(sv.x); a2 = bf_lo(sv.y); a3 = bf_hi(sv.y);
    a4 = bf_lo(sv.z); a5 = bf_hi(sv.z); a6 = bf_lo(sv.w); a7 = bf_hi(sv.w);
  }
  int e0 = offs[i], e1 = offs[i + 1];
  int e = e0;
#pragma unroll 2
  for (; e + 4 <= e1; e += 4) {
    int s = csr[e + q];
    uint4 h = H4[(size_t)s * 16 + k];
    a0 += bf_lo(h.x); a1 += bf_hi(h.x); a2 += bf_lo(h.y); a3 += bf_hi(h.y);
    a4 += bf_lo(h.z); a5 += bf_hi(h.z); a6 += bf_lo(h.w); a7 += bf_hi(h.w);
  }
  int rem = e1 - e;
  if (q < rem) {
    int s = csr[e + q];
    uint4 h = H4[(size_t)s * 16 + k];
    a0 += bf_lo(h.x); a1 += bf_hi(h.x); a2 += bf_lo(h.y); a3 += bf_hi(h.y);
    a4 += bf_lo(h.z); a5 += bf_hi(h.z); a6 += bf_lo(h.w); a7 += bf_hi(h.w);
  }
  // reduce quarters (xor 16, xor 32)
  a0 += __shfl_xor(a0, 16); a1 += __shfl_xor(a1, 16);
  a2 += __shfl_xor(a2, 16); a3 += __shfl_xor(a3, 16);
  a4 += __shfl_xor(a4, 16); a5 += __shfl_xor(a5, 16);
  a6 += __shfl_xor(a6, 16); a7 += __shfl_xor(a7, 16);
  a0 += __shfl_xor(a0, 32); a1 += __shfl_xor(a1, 32);
  a2 += __shfl_xor(a2, 32); a3 += __shfl_xor(a3, 32);
  a4 += __shfl_xor(a4, 32); a5 += __shfl_xor(a5, 32);
  a6 += __shfl_xor(a6, 32); a7 += __shfl_xor(a7, 32);
  if (q == 0) {
    float di = dinv[i];
    const float4* B4 = (const float4*)bias;
    float4 bA = B4[k * 2], bB = B4[k * 2 + 1];
    uint4 r;
    r.x = pack2(fmaxf(bA.x + di * a0, 0.f), fmaxf(bA.y + di * a1, 0.f));
    r.y = pack2(fmaxf(bA.z + di * a2, 0.f), fmaxf(bA.w + di * a3, 0.f));
    r.z = pack2(fmaxf(bB.x + di * a4, 0.f), fmaxf(bB.y + di * a5, 0.f));
    r.w = pack2(fmaxf(bB.z + di * a6, 0.f), fmaxf(bB.w + di * a7, 0.f));
    Ho[(size_t)i * 16 + k] = r;
  }
}

// ---------------- Node-parallel pool: segmented atomic sum ----------------
__global__ __launch_bounds__(256) void k_pool2(const unsigned* __restrict__ H2,
                                               const int* __restrict__ batch,
                                               float* __restrict__ ps, int n) {
  int t = threadIdx.x;
  int ln = t & 63, sub = t >> 6;
  int r0 = blockIdx.x * NPB + sub;
  int rend = min(blockIdx.x * NPB + NPB, n);
  float ax = 0.f, ay = 0.f;
  int curg = -1;
  for (int r = r0; r < rend; r += 4) {
    int g = batch[r];
    if (g != curg) {
      if (curg >= 0) {
        atomicAdd(&ps[curg * 128 + 2 * ln], ax);
        atomicAdd(&ps[curg * 128 + 2 * ln + 1], ay);
      }
      curg = g; ax = 0.f; ay = 0.f;
    }
    unsigned h = H2[(size_t)r * 64 + ln];
    ax += bf_lo(h);
    ay += bf_hi(h);
  }
  if (curg >= 0) {
    atomicAdd(&ps[curg * 128 + 2 * ln], ax);
    atomicAdd(&ps[curg * 128 + 2 * ln + 1], ay);
  }
}

// ---------------- Head: 512 blocks x 192 threads ----------------
__global__ void k_head(const float* __restrict__ ps, const int* __restrict__ gstart,
                       const float* __restrict__ axd,
                       const float* __restrict__ l1W, const float* __restrict__ l1b,
                       const float* __restrict__ axW, const float* __restrict__ axb,
                       const float* __restrict__ l2W, const float* __restrict__ l2b,
                       float* __restrict__ out) {
  int g = blockIdx.x, t = threadIdx.x;
  __shared__ float p[128];
  __shared__ float a[64];
  __shared__ float z[192];
  int c = gstart[g + 1] - gstart[g];
  if (c < 1) c = 1;
  float inv = 1.f / (float)c;
  if (t < 128) p[t] = ps[g * 128 + t] * inv;
  else a[t - 128] = axd[g * 64 + (t - 128)];
  __syncthreads();
  if (t < 128) {
    float acc = l1b[t];
#pragma unroll 4
    for (int kk = 0; kk < 128; kk++) acc += p[kk] * l1W[kk * 128 + t];
    z[t] = acc;
  } else {
    int j = t - 128;
    float acc = axb[j];
#pragma unroll 4
    for (int kk = 0; kk < 64; kk++) acc += a[kk] * axW[kk * 64 + j];
    z[128 + j] = acc;
  }
  __syncthreads();
  if (t < 8) {
    float acc = l2b[t];
#pragma unroll 4
    for (int kk = 0; kk < 192; kk++) acc += z[kk] * l2W[kk * 8 + t];
    out[g * 8 + t] = acc;
  }
}

extern "C" void kernel_launch(void* const* d_in, const int* in_sizes, int n_in,
                              void* d_out, int out_size, void* d_ws, size_t ws_size,
                              hipStream_t stream) {
  const float* x   = (const float*)d_in[0];
  const int*   ei  = (const int*)d_in[1];
  const int*   bat = (const int*)d_in[2];
  const float* axd = (const float*)d_in[3];
  const float* W1  = (const float*)d_in[4];
  const float* b1  = (const float*)d_in[5];
  const float* W2  = (const float*)d_in[6];
  const float* b2  = (const float*)d_in[7];
  const float* l1W = (const float*)d_in[8];
  const float* l1b = (const float*)d_in[9];
  const float* axW = (const float*)d_in[10];
  const float* axb = (const float*)d_in[11];
  const float* l2W = (const float*)d_in[12];
  const float* l2b = (const float*)d_in[13];
  float* out = (float*)d_out;

  int n = in_sizes[0] / NFEAT;   // 50000
  int E = in_sizes[1] / 2;       // 640000
  int G = in_sizes[3] / 64;      // 512

  unsigned short* hbuf  = (unsigned short*)d_ws;           // n*128 bf16
  unsigned short* habuf = hbuf + (size_t)n * NFEAT;        // n*128 bf16
  unsigned short* wt1   = habuf + (size_t)n * NFEAT;       // 16384 bf16
  unsigned short* wt2   = wt1 + 16384;                     // 16384 bf16
  int*   csr    = (int*)(wt2 + 16384);                     // E
  int*   offs   = csr + E;                                 // n+1
  int*   cursor = offs + (n + 1);                          // n
  int*   cnt    = cursor + n;                              // n      <- zeroed
  float* ps     = (float*)(cnt + n);                       // G*128  <- zeroed (contig)
  float* dinv   = (float*)(ps + (size_t)G * 128);          // n
  int*   part   = (int*)(dinv + n);                        // 256
  int*   ppre   = part + 256;                              // 256
  int*   gstart = ppre + 256;                              // G+1

  const int* srcv = ei;
  const int* dstv = ei + E;
  int NB = (n + 255) / 256;

  hipMemsetAsync(cnt, 0, ((size_t)n + (size_t)G * 128) * sizeof(int), stream);
  k_deg<<<(E + 255) / 256, 256, 0, stream>>>(dstv, cnt, E);
  k_part<<<NB, 256, 0, stream>>>(cnt, part, n);
  k_scan1<<<1, 256, 0, stream>>>(part, ppre, NB, offs, n);
  k_offsets<<<NB, 256, 0, stream>>>(cnt, ppre, offs, cursor, dinv, n);
  k_fill<<<(E + 255) / 256, 256, 0, stream>>>(srcv, dstv, cursor, csr, E);
  k_wprep<<<256, 128, 0, stream>>>(W1, W2, wt1, wt2);
  k_gbounds<<<1, 576, 0, stream>>>(bat, gstart, n, G);

  int gb = (n + 63) / 64;
  k_gemm_mfma<true><<<gb, 256, 0, stream>>>(x, (const uint4*)wt1, dinv, hbuf, n);
  k_agg<<<(n + 3) / 4, 256, 0, stream>>>((const uint4*)hbuf, csr, offs, dinv, b1,
                                         (uint4*)habuf, n);
  k_gemm_mfma<false><<<gb, 256, 0, stream>>>(habuf, (const uint4*)wt2, dinv, hbuf, n);
  k_agg<<<(n + 3) / 4, 256, 0, stream>>>((const uint4*)hbuf, csr, offs, dinv, b2,
                                         (uint4*)habuf, n);

  k_pool2<<<(n + NPB - 1) / NPB, 256, 0, stream>>>((const unsigned*)habuf, bat, ps, n);
  k_head<<<G, 192, 0, stream>>>(ps, gstart, axd, l1W, l1b, axW, axb, l2W, l2b, out);
}

// Round 5
// 297.768 us; speedup vs baseline: 1.6021x; 1.0304x over previous
//
#include <hip/hip_runtime.h>

// patient_GCN: 2x GCNConv(128->128) + mean-pool + head.
// R5: agg preloads whole adjacency via one coalesced csr load + __shfl
// (removes csr->gather latency chain); prep kernel fuses zeroing+wprep+gbounds.

#define NFEAT 128
#define NPB 128  // nodes per pool block

typedef __attribute__((ext_vector_type(8))) short bf16x8;
typedef __attribute__((ext_vector_type(4))) float f32x4;

static __device__ __forceinline__ unsigned short f2bf(float f) {
  unsigned u = __float_as_uint(f);
  return (unsigned short)((u + 0x7fffu + ((u >> 16) & 1u)) >> 16);
}
static __device__ __forceinline__ unsigned pack2(float a, float b) {
  return (unsigned)f2bf(a) | ((unsigned)f2bf(b) << 16);
}
static __device__ __forceinline__ float bf_lo(unsigned u) { return __uint_as_float(u << 16); }
static __device__ __forceinline__ float bf_hi(unsigned u) { return __uint_as_float(u & 0xffff0000u); }

// ---------------- prep: zero cnt+ps, transpose W1/W2 to bf16, graph bounds ----
__global__ void k_prep(const float* __restrict__ W1, const float* __restrict__ W2,
                       unsigned short* __restrict__ WT1, unsigned short* __restrict__ WT2,
                       const int* __restrict__ batch, int* __restrict__ gstart,
                       int* __restrict__ cnt, float* __restrict__ ps,
                       int n, int G, int nb_cnt, int nb_ps) {
  int b = blockIdx.x, t = threadIdx.x;
  if (b < nb_cnt) {
    int i = b * 256 + t;
    if (i < n) cnt[i] = 0;
  } else if (b < nb_cnt + nb_ps) {
    int i = (b - nb_cnt) * 256 + t;
    if (i < G * 128) ps[i] = 0.f;
  } else if (b < nb_cnt + nb_ps + 128) {
    int e = (b - nb_cnt - nb_ps) * 256 + t;  // 32768 total
    int w = e >> 14;
    int r = (e >> 7) & 127, k = e & 127;
    if (w == 0) WT1[r * 128 + k] = f2bf(W1[k * 128 + r]);
    else        WT2[r * 128 + k] = f2bf(W2[k * 128 + r]);
  } else {
    int g = (b - nb_cnt - nb_ps - 128) * 256 + t;
    if (g > G) return;
    if (g == G) { gstart[g] = n; return; }
    int lo = 0, hi = n;
    while (lo < hi) {
      int mid = (lo + hi) >> 1;
      if (batch[mid] < g) lo = mid + 1; else hi = mid;
    }
    gstart[g] = lo;
  }
}

// ---------------- CSR build ----------------
__global__ void k_deg(const int* __restrict__ dst, int* __restrict__ cnt, int E) {
  int e = blockIdx.x * 256 + threadIdx.x;
  if (e < E) atomicAdd(&cnt[dst[e]], 1);
}

__global__ void k_part(const int* __restrict__ cnt, int* __restrict__ part, int n) {
  __shared__ int s[256];
  int t = threadIdx.x;
  int idx = blockIdx.x * 256 + t;
  s[t] = (idx < n) ? cnt[idx] : 0;
  __syncthreads();
  for (int o = 128; o > 0; o >>= 1) {
    if (t < o) s[t] += s[t + o];
    __syncthreads();
  }
  if (t == 0) part[blockIdx.x] = s[0];
}

__global__ void k_scan1(const int* __restrict__ part, int* __restrict__ ppre,
                        int NB, int* __restrict__ offs, int n) {
  __shared__ int s[256];
  int t = threadIdx.x;
  int v = (t < NB) ? part[t] : 0;
  s[t] = v;
  __syncthreads();
  for (int o = 1; o < 256; o <<= 1) {
    int tmp = (t >= o) ? s[t - o] : 0;
    __syncthreads();
    s[t] += tmp;
    __syncthreads();
  }
  if (t < NB) ppre[t] = s[t] - v;
  if (t == NB - 1) offs[n] = s[t];
}

__global__ void k_offsets(const int* __restrict__ cnt, const int* __restrict__ ppre,
                          int* __restrict__ offs, int* __restrict__ cursor,
                          float* __restrict__ dinv, int n) {
  __shared__ int s[256];
  int t = threadIdx.x;
  int idx = blockIdx.x * 256 + t;
  int v = (idx < n) ? cnt[idx] : 0;
  s[t] = v;
  __syncthreads();
  for (int o = 1; o < 256; o <<= 1) {
    int tmp = (t >= o) ? s[t - o] : 0;
    __syncthreads();
    s[t] += tmp;
    __syncthreads();
  }
  if (idx < n) {
    int off = ppre[blockIdx.x] + s[t] - v;
    offs[idx] = off;
    cursor[idx] = off;
    dinv[idx] = rsqrtf((float)(v + 1));
  }
}

__global__ void k_fill(const int* __restrict__ src, const int* __restrict__ dst,
                       int* __restrict__ cursor, int* __restrict__ csr, int E) {
  int e = blockIdx.x * 256 + threadIdx.x;
  if (e < E) {
    int p = atomicAdd(&cursor[dst[e]], 1);
    csr[p] = src[e];
  }
}

// ---------------- GEMM: Hs[M,128](bf16) = dinv[m] * (X[M,128] @ W) ----------------
template <bool FP32IN>
__global__ __launch_bounds__(256) void k_gemm_mfma(const void* __restrict__ Xv,
                                                   const uint4* __restrict__ WT4,
                                                   const float* __restrict__ dinv,
                                                   unsigned short* __restrict__ H,
                                                   int M) {
  __shared__ __align__(16) unsigned short sW[128 * 136];
  __shared__ __align__(16) unsigned short sX[64 * 136];
  int tid = threadIdx.x;
  int m0 = blockIdx.x * 64;

#pragma unroll
  for (int t = 0; t < 8; t++) {
    int idx = tid + t * 256;
    int n = idx >> 4, c8 = idx & 15;
    *(uint4*)(sW + n * 136 + c8 * 8) = WT4[idx];
  }
  if (FP32IN) {
    const float4* X4 = (const float4*)Xv;
#pragma unroll
    for (int t = 0; t < 8; t++) {
      int idx = tid + t * 256;
      int r = idx >> 5, c4 = idx & 31;
      int m = m0 + r;
      float4 v = make_float4(0.f, 0.f, 0.f, 0.f);
      if (m < M) v = X4[(size_t)m * 32 + c4];
      unsigned short* p = sX + r * 136 + c4 * 4;
      *(ushort2*)(p) = make_ushort2(f2bf(v.x), f2bf(v.y));
      *(ushort2*)(p + 2) = make_ushort2(f2bf(v.z), f2bf(v.w));
    }
  } else {
    const uint4* X4 = (const uint4*)Xv;
#pragma unroll
    for (int t = 0; t < 4; t++) {
      int idx = tid + t * 256;
      int r = idx >> 4, c8 = idx & 15;
      int m = m0 + r;
      uint4 v = make_uint4(0u, 0u, 0u, 0u);
      if (m < M) v = X4[(size_t)m * 16 + c8];
      *(uint4*)(sX + r * 136 + c8 * 8) = v;
    }
  }
  __syncthreads();

  int lane = tid & 63, wv = tid >> 6;
  int ln15 = lane & 15, q = lane >> 4;
  bf16x8 afrag[4];
#pragma unroll
  for (int c = 0; c < 4; c++)
    afrag[c] = *(const bf16x8*)(sX + (wv * 16 + ln15) * 136 + c * 32 + q * 8);

  int r0 = m0 + wv * 16 + q * 4;
  float dv[4];
#pragma unroll
  for (int rr = 0; rr < 4; rr++) dv[rr] = (r0 + rr < M) ? dinv[r0 + rr] : 0.f;

#pragma unroll
  for (int j = 0; j < 8; j++) {
    f32x4 acc = {0.f, 0.f, 0.f, 0.f};
#pragma unroll
    for (int c = 0; c < 4; c++) {
      bf16x8 bfrag = *(const bf16x8*)(sW + (j * 16 + ln15) * 136 + c * 32 + q * 8);
      acc = __builtin_amdgcn_mfma_f32_16x16x32_bf16(afrag[c], bfrag, acc, 0, 0, 0);
    }
    int col = j * 16 + ln15;
#pragma unroll
    for (int rr = 0; rr < 4; rr++) {
      int m = r0 + rr;
      if (m < M) H[(size_t)m * 128 + col] = f2bf(dv[rr] * acc[rr]);
    }
  }
}

// ---------------- Aggregation: adjacency preloaded, shfl-fed gathers ----------
// out[i] = relu(b + dinv[i]*(Hs[i] + sum_{s in N(i)} Hs[s]))
__global__ __launch_bounds__(256) void k_agg(const uint4* __restrict__ H4,
                                             const int* __restrict__ csr,
                                             const int* __restrict__ offs,
                                             const float* __restrict__ dinv,
                                             const float* __restrict__ bias,
                                             uint4* __restrict__ Ho, int n) {
  int lane = threadIdx.x & 63;
  int i = blockIdx.x * 4 + (threadIdx.x >> 6);
  if (i >= n) return;
  int q = lane >> 4, k = lane & 15;
  int e0 = offs[i], e1 = offs[i + 1];
  int deg = e1 - e0;
  // whole adjacency list in one coalesced load (deg<=64 in practice)
  int adj = (lane < deg) ? csr[e0 + lane] : 0;

  float a0 = 0.f, a1 = 0.f, a2 = 0.f, a3 = 0.f, a4 = 0.f, a5 = 0.f, a6 = 0.f, a7 = 0.f;
  if (q == 0) {  // self row
    uint4 sv = H4[(size_t)i * 16 + k];
    a0 = bf_lo(sv.x); a1 = bf_hi(sv.x); a2 = bf_lo(sv.y); a3 = bf_hi(sv.y);
    a4 = bf_lo(sv.z); a5 = bf_hi(sv.z); a6 = bf_lo(sv.w); a7 = bf_hi(sv.w);
  }
  int dcap = deg < 64 ? deg : 64;
  int j = 0;
#pragma unroll 2
  for (; j + 4 <= dcap; j += 4) {
    int s = __shfl(adj, j + q);
    uint4 h = H4[(size_t)s * 16 + k];
    a0 += bf_lo(h.x); a1 += bf_hi(h.x); a2 += bf_lo(h.y); a3 += bf_hi(h.y);
    a4 += bf_lo(h.z); a5 += bf_hi(h.z); a6 += bf_lo(h.w); a7 += bf_hi(h.w);
  }
  int rem = dcap - j;
  if (rem > 0) {
    int s = __shfl(adj, j + (q < rem ? q : rem - 1));
    if (q < rem) {
      uint4 h = H4[(size_t)s * 16 + k];
      a0 += bf_lo(h.x); a1 += bf_hi(h.x); a2 += bf_lo(h.y); a3 += bf_hi(h.y);
      a4 += bf_lo(h.z); a5 += bf_hi(h.z); a6 += bf_lo(h.w); a7 += bf_hi(h.w);
    }
  }
  // rare tail deg>64: direct csr loads
  int e = e0 + 64;
  for (; e + 4 <= e1; e += 4) {
    int s = csr[e + q];
    uint4 h = H4[(size_t)s * 16 + k];
    a0 += bf_lo(h.x); a1 += bf_hi(h.x); a2 += bf_lo(h.y); a3 += bf_hi(h.y);
    a4 += bf_lo(h.z); a5 += bf_hi(h.z); a6 += bf_lo(h.w); a7 += bf_hi(h.w);
  }
  if (e < e1 && q < e1 - e) {
    int s = csr[e + q];
    uint4 h = H4[(size_t)s * 16 + k];
    a0 += bf_lo(h.x); a1 += bf_hi(h.x); a2 += bf_lo(h.y); a3 += bf_hi(h.y);
    a4 += bf_lo(h.z); a5 += bf_hi(h.z); a6 += bf_lo(h.w); a7 += bf_hi(h.w);
  }
  // reduce quarters (xor 16, xor 32)
  a0 += __shfl_xor(a0, 16); a1 += __shfl_xor(a1, 16);
  a2 += __shfl_xor(a2, 16); a3 += __shfl_xor(a3, 16);
  a4 += __shfl_xor(a4, 16); a5 += __shfl_xor(a5, 16);
  a6 += __shfl_xor(a6, 16); a7 += __shfl_xor(a7, 16);
  a0 += __shfl_xor(a0, 32); a1 += __shfl_xor(a1, 32);
  a2 += __shfl_xor(a2, 32); a3 += __shfl_xor(a3, 32);
  a4 += __shfl_xor(a4, 32); a5 += __shfl_xor(a5, 32);
  a6 += __shfl_xor(a6, 32); a7 += __shfl_xor(a7, 32);
  if (q == 0) {
    float di = dinv[i];
    const float4* B4 = (const float4*)bias;
    float4 bA = B4[k * 2], bB = B4[k * 2 + 1];
    uint4 r;
    r.x = pack2(fmaxf(bA.x + di * a0, 0.f), fmaxf(bA.y + di * a1, 0.f));
    r.y = pack2(fmaxf(bA.z + di * a2, 0.f), fmaxf(bA.w + di * a3, 0.f));
    r.z = pack2(fmaxf(bB.x + di * a4, 0.f), fmaxf(bB.y + di * a5, 0.f));
    r.w = pack2(fmaxf(bB.z + di * a6, 0.f), fmaxf(bB.w + di * a7, 0.f));
    Ho[(size_t)i * 16 + k] = r;
  }
}

// ---------------- Node-parallel pool: segmented atomic sum ----------------
__global__ __launch_bounds__(256) void k_pool2(const unsigned* __restrict__ H2,
                                               const int* __restrict__ batch,
                                               float* __restrict__ ps, int n) {
  int t = threadIdx.x;
  int ln = t & 63, sub = t >> 6;
  int r0 = blockIdx.x * NPB + sub;
  int rend = min(blockIdx.x * NPB + NPB, n);
  float ax = 0.f, ay = 0.f;
  int curg = -1;
  for (int r = r0; r < rend; r += 4) {
    int g = batch[r];
    if (g != curg) {
      if (curg >= 0) {
        atomicAdd(&ps[curg * 128 + 2 * ln], ax);
        atomicAdd(&ps[curg * 128 + 2 * ln + 1], ay);
      }
      curg = g; ax = 0.f; ay = 0.f;
    }
    unsigned h = H2[(size_t)r * 64 + ln];
    ax += bf_lo(h);
    ay += bf_hi(h);
  }
  if (curg >= 0) {
    atomicAdd(&ps[curg * 128 + 2 * ln], ax);
    atomicAdd(&ps[curg * 128 + 2 * ln + 1], ay);
  }
}

// ---------------- Head: 512 blocks x 192 threads ----------------
__global__ void k_head(const float* __restrict__ ps, const int* __restrict__ gstart,
                       const float* __restrict__ axd,
                       const float* __restrict__ l1W, const float* __restrict__ l1b,
                       const float* __restrict__ axW, const float* __restrict__ axb,
                       const float* __restrict__ l2W, const float* __restrict__ l2b,
                       float* __restrict__ out) {
  int g = blockIdx.x, t = threadIdx.x;
  __shared__ float p[128];
  __shared__ float a[64];
  __shared__ float z[192];
  int c = gstart[g + 1] - gstart[g];
  if (c < 1) c = 1;
  float inv = 1.f / (float)c;
  if (t < 128) p[t] = ps[g * 128 + t] * inv;
  else a[t - 128] = axd[g * 64 + (t - 128)];
  __syncthreads();
  if (t < 128) {
    float acc = l1b[t];
#pragma unroll 4
    for (int kk = 0; kk < 128; kk++) acc += p[kk] * l1W[kk * 128 + t];
    z[t] = acc;
  } else {
    int j = t - 128;
    float acc = axb[j];
#pragma unroll 4
    for (int kk = 0; kk < 64; kk++) acc += a[kk] * axW[kk * 64 + j];
    z[128 + j] = acc;
  }
  __syncthreads();
  if (t < 8) {
    float acc = l2b[t];
#pragma unroll 4
    for (int kk = 0; kk < 192; kk++) acc += z[kk] * l2W[kk * 8 + t];
    out[g * 8 + t] = acc;
  }
}

extern "C" void kernel_launch(void* const* d_in, const int* in_sizes, int n_in,
                              void* d_out, int out_size, void* d_ws, size_t ws_size,
                              hipStream_t stream) {
  const float* x   = (const float*)d_in[0];
  const int*   ei  = (const int*)d_in[1];
  const int*   bat = (const int*)d_in[2];
  const float* axd = (const float*)d_in[3];
  const float* W1  = (const float*)d_in[4];
  const float* b1  = (const float*)d_in[5];
  const float* W2  = (const float*)d_in[6];
  const float* b2  = (const float*)d_in[7];
  const float* l1W = (const float*)d_in[8];
  const float* l1b = (const float*)d_in[9];
  const float* axW = (const float*)d_in[10];
  const float* axb = (const float*)d_in[11];
  const float* l2W = (const float*)d_in[12];
  const float* l2b = (const float*)d_in[13];
  float* out = (float*)d_out;

  int n = in_sizes[0] / NFEAT;   // 50000
  int E = in_sizes[1] / 2;       // 640000
  int G = in_sizes[3] / 64;      // 512

  unsigned short* hbuf  = (unsigned short*)d_ws;           // n*128 bf16
  unsigned short* habuf = hbuf + (size_t)n * NFEAT;        // n*128 bf16
  unsigned short* wt1   = habuf + (size_t)n * NFEAT;       // 16384 bf16
  unsigned short* wt2   = wt1 + 16384;                     // 16384 bf16
  int*   csr    = (int*)(wt2 + 16384);                     // E
  int*   offs   = csr + E;                                 // n+1
  int*   cursor = offs + (n + 1);                          // n
  int*   cnt    = cursor + n;                              // n      (zeroed in prep)
  float* ps     = (float*)(cnt + n);                       // G*128  (zeroed in prep)
  float* dinv   = (float*)(ps + (size_t)G * 128);          // n
  int*   part   = (int*)(dinv + n);                        // 256
  int*   ppre   = part + 256;                              // 256
  int*   gstart = ppre + 256;                              // G+1

  const int* srcv = ei;
  const int* dstv = ei + E;
  int NB = (n + 255) / 256;
  int nb_cnt = NB;                       // zero cnt
  int nb_ps  = (G * 128 + 255) / 256;    // zero ps
  int nb_g   = (G + 1 + 255) / 256;      // gbounds
  int prep_blocks = nb_cnt + nb_ps + 128 + nb_g;

  k_prep<<<prep_blocks, 256, 0, stream>>>(W1, W2, wt1, wt2, bat, gstart, cnt, ps,
                                          n, G, nb_cnt, nb_ps);
  k_deg<<<(E + 255) / 256, 256, 0, stream>>>(dstv, cnt, E);
  k_part<<<NB, 256, 0, stream>>>(cnt, part, n);
  k_scan1<<<1, 256, 0, stream>>>(part, ppre, NB, offs, n);
  k_offsets<<<NB, 256, 0, stream>>>(cnt, ppre, offs, cursor, dinv, n);
  k_fill<<<(E + 255) / 256, 256, 0, stream>>>(srcv, dstv, cursor, csr, E);

  int gb = (n + 63) / 64;
  k_gemm_mfma<true><<<gb, 256, 0, stream>>>(x, (const uint4*)wt1, dinv, hbuf, n);
  k_agg<<<(n + 3) / 4, 256, 0, stream>>>((const uint4*)hbuf, csr, offs, dinv, b1,
                                         (uint4*)habuf, n);
  k_gemm_mfma<false><<<gb, 256, 0, stream>>>(habuf, (const uint4*)wt2, dinv, hbuf, n);
  k_agg<<<(n + 3) / 4, 256, 0, stream>>>((const uint4*)hbuf, csr, offs, dinv, b2,
                                         (uint4*)habuf, n);

  k_pool2<<<(n + NPB - 1) / NPB, 256, 0, stream>>>((const unsigned*)habuf, bat, ps, n);
  k_head<<<G, 192, 0, stream>>>(ps, gstart, axd, l1W, l1b, axW, axb, l2W, l2b, out);
}